// Round 1
// 533.577 us; speedup vs baseline: 1.0837x; 1.0837x over previous
//
#include <hip/hip_runtime.h>
#include <cmath>

constexpr int B = 32, T = 1024, J = 256, D = 512;

typedef __attribute__((ext_vector_type(8))) short bf16x8;
typedef __attribute__((ext_vector_type(4))) float f32x4;
typedef __attribute__((ext_vector_type(8))) unsigned short u16x8;
typedef __attribute__((ext_vector_type(4))) unsigned short u16x4;
using u16 = unsigned short;

// ---- workspace layout (float units) ----
constexpr size_t OFF_S   = 0;                                 // S[b,t,j] fp32
constexpr size_t OFF_CH  = OFF_S   + (size_t)B*T*J;           // context hi bf16
constexpr size_t OFF_CL  = OFF_CH  + (size_t)B*T*D/2;         // context lo bf16
constexpr size_t OFF_QPH = OFF_CL  + (size_t)B*T*D/2;         // (q*w3) hi
constexpr size_t OFF_QPL = OFF_QPH + (size_t)B*J*D/2;         // (q*w3) lo
constexpr size_t OFF_QTH = OFF_QPL + (size_t)B*J*D/2;         // q^T hi  [D][J]
constexpr size_t OFF_QTL = OFF_QTH + (size_t)B*J*D/2;         // q^T lo
constexpr size_t OFF_PH  = OFF_QTL + (size_t)B*J*D/2;         // P hi    [T][J]
constexpr size_t OFF_PLO = OFF_PH  + (size_t)B*T*J/2;         // P lo
constexpr size_t OFF_RT  = OFF_PLO + (size_t)B*T*J/2;         // context@w1
constexpr size_t OFF_CT  = OFF_RT  + (size_t)B*T;             // query@w2
constexpr size_t OFF_M   = OFF_CT  + (size_t)B*J;             // col max
constexpr size_t OFF_IL  = OFF_M   + (size_t)B*J;             // 1/col sumexp
constexpr size_t OFF_RM  = OFF_IL  + (size_t)B*J;             // row max
constexpr size_t OFF_BT  = OFF_RM  + (size_t)B*T;             // b_t softmax
constexpr size_t OFF_H   = OFF_BT  + (size_t)B*T;             // h[b,d]
constexpr size_t OFF_PM  = OFF_H   + (size_t)B*D;             // partial col max (16 mblk)
constexpr size_t OFF_PL2 = OFF_PM  + (size_t)B*16*J;          // partial col sumexp

__device__ __forceinline__ u16 f2bf(float x) {
  unsigned u = __float_as_uint(x);
  u += 0x7FFFu + ((u >> 16) & 1u);
  return (u16)(u >> 16);
}
__device__ __forceinline__ float bf2f(u16 h) {
  return __uint_as_float((unsigned)h << 16);
}

// ---------- context prep: rt = c.w1 ; c -> hi/lo bf16 ----------
__global__ void k_prep_c(const float* __restrict__ ctx, const float* __restrict__ w_alpha,
                         float* __restrict__ rt, u16* __restrict__ ch, u16* __restrict__ cl) {
  int wid = threadIdx.x >> 6, lane = threadIdx.x & 63;
  size_t row = (size_t)blockIdx.x * 4 + wid;
  const float4* s4 = (const float4*)(ctx + row * D);
  const float4* w4 = (const float4*)w_alpha;
  float4 a0 = s4[lane*2], a1 = s4[lane*2+1];
  float4 b0 = w4[lane*2], b1 = w4[lane*2+1];
  float acc = a0.x*b0.x + a0.y*b0.y + a0.z*b0.z + a0.w*b0.w
            + a1.x*b1.x + a1.y*b1.y + a1.z*b1.z + a1.w*b1.w;
  float v[8] = {a0.x,a0.y,a0.z,a0.w,a1.x,a1.y,a1.z,a1.w};
  u16x8 hv, lv;
  #pragma unroll
  for (int i = 0; i < 8; ++i) {
    u16 hb = f2bf(v[i]);
    hv[i] = hb;
    lv[i] = f2bf(v[i] - bf2f(hb));
  }
  *(u16x8*)(ch + row*D + lane*8) = hv;
  *(u16x8*)(cl + row*D + lane*8) = lv;
  #pragma unroll
  for (int off = 32; off; off >>= 1) acc += __shfl_down(acc, off);
  if (lane == 0) rt[row] = acc;
}

// ---------- query prep: ct = q.w2 ; q*w3 -> hi/lo bf16 ----------
__global__ void k_prep_q(const float* __restrict__ q, const float* __restrict__ w_alpha,
                         float* __restrict__ ct, u16* __restrict__ qph, u16* __restrict__ qpl) {
  int wid = threadIdx.x >> 6, lane = threadIdx.x & 63;
  size_t row = (size_t)blockIdx.x * 4 + wid;
  const float4* q4 = (const float4*)(q + row * D);
  const float4* w2 = (const float4*)(w_alpha + D);
  const float4* w3 = (const float4*)(w_alpha + 2 * D);
  float4 a0 = q4[lane*2], a1 = q4[lane*2+1];
  float4 b0 = w2[lane*2], b1 = w2[lane*2+1];
  float4 c0 = w3[lane*2], c1 = w3[lane*2+1];
  float acc = a0.x*b0.x + a0.y*b0.y + a0.z*b0.z + a0.w*b0.w
            + a1.x*b1.x + a1.y*b1.y + a1.z*b1.z + a1.w*b1.w;
  float v[8] = {a0.x*c0.x, a0.y*c0.y, a0.z*c0.z, a0.w*c0.w,
                a1.x*c1.x, a1.y*c1.y, a1.z*c1.z, a1.w*c1.w};
  u16x8 hv, lv;
  #pragma unroll
  for (int i = 0; i < 8; ++i) {
    u16 hb = f2bf(v[i]);
    hv[i] = hb;
    lv[i] = f2bf(v[i] - bf2f(hb));
  }
  *(u16x8*)(qph + row*D + lane*8) = hv;
  *(u16x8*)(qpl + row*D + lane*8) = lv;
  #pragma unroll
  for (int off = 32; off; off >>= 1) acc += __shfl_down(acc, off);
  if (lane == 0) ct[row] = acc;
}

// ---------- query transpose: q[J][D] -> qt hi/lo [D][J] ----------
__global__ void k_qt(const float* __restrict__ q, u16* __restrict__ qth, u16* __restrict__ qtl) {
  __shared__ float tl[64][65];
  int b = blockIdx.y;
  int j0 = (blockIdx.x & 3) * 64;
  int d0 = (blockIdx.x >> 2) * 64;
  int r = threadIdx.x >> 4, c = threadIdx.x & 15;
  #pragma unroll
  for (int rr = 0; rr < 4; ++rr) {
    int jl = r + rr*16;
    float4 v = *(const float4*)(q + ((size_t)b*J + j0 + jl)*D + d0 + c*4);
    tl[jl][c*4+0] = v.x; tl[jl][c*4+1] = v.y; tl[jl][c*4+2] = v.z; tl[jl][c*4+3] = v.w;
  }
  __syncthreads();
  #pragma unroll
  for (int rr = 0; rr < 4; ++rr) {
    int dl = r + rr*16;
    u16x4 hv, lv;
    #pragma unroll
    for (int k = 0; k < 4; ++k) {
      float v = tl[c*4+k][dl];
      u16 hb = f2bf(v);
      hv[k] = hb;
      lv[k] = f2bf(v - bf2f(hb));
    }
    size_t o = ((size_t)b*D + d0 + dl)*J + j0 + c*4;
    *(u16x4*)(qth + o) = hv;
    *(u16x4*)(qtl + o) = lv;
  }
}

// ---------- shared MFMA machinery (bf16x3 error-compensated) ----------
struct FragSet { bf16x8 ah[4], al[4], bh[4], bl[4]; };

__device__ __forceinline__ void ld_frags(FragSet& f,
    const u16* __restrict__ Ah, const u16* __restrict__ Al,
    const u16* __restrict__ Bh, const u16* __restrict__ Bl,
    int ld, int k0) {
  #pragma unroll
  for (int i = 0; i < 4; ++i) {
    f.ah[i] = *(const bf16x8*)(Ah + (size_t)(i*16)*ld + k0);
    f.al[i] = *(const bf16x8*)(Al + (size_t)(i*16)*ld + k0);
    f.bh[i] = *(const bf16x8*)(Bh + (size_t)(i*16)*ld + k0);
    f.bl[i] = *(const bf16x8*)(Bl + (size_t)(i*16)*ld + k0);
  }
}

__device__ __forceinline__ void mm3(f32x4 acc[4][4], const FragSet& f) {
  #pragma unroll
  for (int i = 0; i < 4; ++i)
    #pragma unroll
    for (int j = 0; j < 4; ++j) {
      f32x4 a = acc[i][j];
      a = __builtin_amdgcn_mfma_f32_16x16x32_bf16(f.ah[i], f.bh[j], a, 0, 0, 0);
      a = __builtin_amdgcn_mfma_f32_16x16x32_bf16(f.ah[i], f.bl[j], a, 0, 0, 0);
      a = __builtin_amdgcn_mfma_f32_16x16x32_bf16(f.al[i], f.bh[j], a, 0, 0, 0);
      acc[i][j] = a;
    }
}

// ---------- S = c @ qp^T + rt + ct, fused col-stats partials + full row-max ----------
// block: 64(M=t) x 256(N=j=full), 4 waves side-by-side in N, wave = 64x64
__global__ __launch_bounds__(256)
void k_sgemm_mfma(const u16* __restrict__ ch, const u16* __restrict__ cl,
                  const u16* __restrict__ qph, const u16* __restrict__ qpl,
                  const float* __restrict__ rt, const float* __restrict__ ct,
                  float* __restrict__ S, float* __restrict__ pm, float* __restrict__ pl,
                  float* __restrict__ rm) {
  __shared__ float rmx[4][64];
  const int b = blockIdx.y, mblk = blockIdx.x;
  const int m0 = mblk * 64;
  const int w = threadIdx.x >> 6, lane = threadIdx.x & 63;
  const int lr = lane & 15, lg = lane >> 4;
  const int n0 = w * 64;
  const u16* Ah = ch  + ((size_t)b*T + m0 + lr)*D + lg*8;
  const u16* Al = cl  + ((size_t)b*T + m0 + lr)*D + lg*8;
  const u16* Bh = qph + ((size_t)b*J + n0 + lr)*D + lg*8;
  const u16* Bl = qpl + ((size_t)b*J + n0 + lr)*D + lg*8;
  f32x4 acc[4][4];
  #pragma unroll
  for (int i = 0; i < 4; ++i)
    #pragma unroll
    for (int j = 0; j < 4; ++j) acc[i][j] = (f32x4){0.f, 0.f, 0.f, 0.f};
  FragSet f0, f1;
  ld_frags(f0, Ah, Al, Bh, Bl, D, 0);
  for (int k0 = 0; k0 < D; k0 += 64) {
    ld_frags(f1, Ah, Al, Bh, Bl, D, k0 + 32);
    mm3(acc, f0);
    int kn = (k0 + 64 < D) ? k0 + 64 : 0;   // tail reload is harmless (never consumed)
    ld_frags(f0, Ah, Al, Bh, Bl, D, kn);
    mm3(acc, f1);
  }
  // add rt[t] + ct[j] in place
  #pragma unroll
  for (int mi = 0; mi < 4; ++mi) {
    float rv[4];
    #pragma unroll
    for (int r = 0; r < 4; ++r) rv[r] = rt[(size_t)b*T + m0 + mi*16 + lg*4 + r];
    #pragma unroll
    for (int nj = 0; nj < 4; ++nj) {
      float cv = ct[(size_t)b*J + n0 + nj*16 + lr];
      #pragma unroll
      for (int r = 0; r < 4; ++r) acc[mi][nj][r] += rv[r] + cv;
    }
  }
  // store S
  float* Sb = S + (size_t)b*T*J;
  #pragma unroll
  for (int mi = 0; mi < 4; ++mi)
    #pragma unroll
    for (int r = 0; r < 4; ++r) {
      size_t ro = (size_t)(m0 + mi*16 + lg*4 + r) * J;
      #pragma unroll
      for (int nj = 0; nj < 4; ++nj)
        Sb[ro + n0 + nj*16 + lr] = acc[mi][nj][r];
    }
  // column partial stats (max + sumexp over this block's 64 rows)
  #pragma unroll
  for (int nj = 0; nj < 4; ++nj) {
    float m = -INFINITY;
    #pragma unroll
    for (int mi = 0; mi < 4; ++mi)
      #pragma unroll
      for (int r = 0; r < 4; ++r) m = fmaxf(m, acc[mi][nj][r]);
    m = fmaxf(m, __shfl_xor(m, 16));
    m = fmaxf(m, __shfl_xor(m, 32));
    float s = 0.f;
    #pragma unroll
    for (int mi = 0; mi < 4; ++mi)
      #pragma unroll
      for (int r = 0; r < 4; ++r) s += __expf(acc[mi][nj][r] - m);
    s += __shfl_xor(s, 16);
    s += __shfl_xor(s, 32);
    if (lg == 0) {
      pm[((size_t)b*16 + mblk)*J + n0 + nj*16 + lr] = m;
      pl[((size_t)b*16 + mblk)*J + n0 + nj*16 + lr] = s;
    }
  }
  // full row max (block spans all J=256)
  #pragma unroll
  for (int mi = 0; mi < 4; ++mi)
    #pragma unroll
    for (int r = 0; r < 4; ++r) {
      float m = -INFINITY;
      #pragma unroll
      for (int nj = 0; nj < 4; ++nj) m = fmaxf(m, acc[mi][nj][r]);
      m = fmaxf(m, __shfl_xor(m, 1));
      m = fmaxf(m, __shfl_xor(m, 2));
      m = fmaxf(m, __shfl_xor(m, 4));
      m = fmaxf(m, __shfl_xor(m, 8));
      if (lr == 0) rmx[w][mi*16 + lg*4 + r] = m;
    }
  __syncthreads();
  if (threadIdx.x < 64) {
    float m = fmaxf(fmaxf(rmx[0][threadIdx.x], rmx[1][threadIdx.x]),
                    fmaxf(rmx[2][threadIdx.x], rmx[3][threadIdx.x]));
    rm[(size_t)b*T + m0 + threadIdx.x] = m;
  }
}

// ---------- combine 16 column partials ----------
__global__ void k_colcombine(const float* __restrict__ pm, const float* __restrict__ pl,
                             float* __restrict__ mcol, float* __restrict__ invl) {
  int b = blockIdx.x, j = threadIdx.x;
  float m = -INFINITY, l = 0.f;
  for (int c = 0; c < 16; ++c) {
    float pmv = pm[((size_t)b * 16 + c) * J + j];
    float plv = pl[((size_t)b * 16 + c) * J + j];
    float mn = fmaxf(m, pmv);
    l = l * __expf(m - mn) + plv * __expf(pmv - mn);
    m = mn;
  }
  mcol[b * J + j] = m;
  invl[b * J + j] = 1.f / l;
}

// ---------- b_t = softmax over t of rowmax ----------
__global__ void k_btsm(const float* __restrict__ rm, float* __restrict__ bt) {
  __shared__ float red[4];
  int b = blockIdx.x, tid = threadIdx.x;
  int wid = tid >> 6, lane = tid & 63;
  float4 x = ((const float4*)(rm + (size_t)b * T))[tid];
  float m = fmaxf(fmaxf(x.x, x.y), fmaxf(x.z, x.w));
  #pragma unroll
  for (int off = 32; off; off >>= 1) m = fmaxf(m, __shfl_down(m, off));
  if (lane == 0) red[wid] = m;
  __syncthreads();
  float M = fmaxf(fmaxf(red[0], red[1]), fmaxf(red[2], red[3]));
  float e0 = __expf(x.x - M), e1 = __expf(x.y - M), e2 = __expf(x.z - M), e3 = __expf(x.w - M);
  float s = e0 + e1 + e2 + e3;
  #pragma unroll
  for (int off = 32; off; off >>= 1) s += __shfl_down(s, off);
  __syncthreads();
  if (lane == 0) red[wid] = s;
  __syncthreads();
  float inv = 1.f / (red[0] + red[1] + red[2] + red[3]);
  ((float4*)(bt + (size_t)b * T))[tid] = make_float4(e0 * inv, e1 * inv, e2 * inv, e3 * inv);
}

// ---------- h[b,d] = sum_t bt * context ----------
__global__ void k_h(const float* __restrict__ C, const float* __restrict__ bt,
                    float* __restrict__ h) {
  int b = blockIdx.y, chunk = blockIdx.x, tid = threadIdx.x;
  const float* Cb = C + (size_t)b * T * D + (size_t)chunk * 128 * D;
  const float* wb = bt + b * T + chunk * 128;
  float2 acc = make_float2(0.f, 0.f);
  for (int t = 0; t < 128; ++t) {
    float w = wb[t];
    float2 v = ((const float2*)(Cb + (size_t)t * D))[tid];
    acc.x = fmaf(w, v.x, acc.x);
    acc.y = fmaf(w, v.y, acc.y);
  }
  atomicAdd(&h[b * D + tid * 2],     acc.x);
  atomicAdd(&h[b * D + tid * 2 + 1], acc.y);
}

// ---------- P = exp(S - mcol)*invl -> hi/lo bf16 ----------
__global__ void k_pexp(const float* __restrict__ S, const float* __restrict__ mcol,
                       const float* __restrict__ invl,
                       u16* __restrict__ ph, u16* __restrict__ plo) {
  int wid = threadIdx.x >> 6, lane = threadIdx.x & 63;
  size_t row = (size_t)blockIdx.x * 4 + wid;     // global row = b*T + t
  int b = (int)(row >> 10);                      // T = 1024
  float4 s  = ((const float4*)(S + row * J))[lane];
  float4 mv = ((const float4*)(mcol + (size_t)b * J))[lane];
  float4 iv = ((const float4*)(invl + (size_t)b * J))[lane];
  float p[4] = {__expf(s.x - mv.x) * iv.x, __expf(s.y - mv.y) * iv.y,
                __expf(s.z - mv.z) * iv.z, __expf(s.w - mv.w) * iv.w};
  u16x4 hv, lv;
  #pragma unroll
  for (int i = 0; i < 4; ++i) {
    u16 hb = f2bf(p[i]);
    hv[i] = hb;
    lv[i] = f2bf(p[i] - bf2f(hb));
  }
  *(u16x4*)(ph  + row * J + lane * 4) = hv;
  *(u16x4*)(plo + row * J + lane * 4) = lv;
}

// ---------- U = P @ query fused with G assembly (bf16x3 MFMA) ----------
// block: 64(M=t) x 256(N=d), 4 waves in N; grid.x = 16 mblk * 2 nblk
__global__ __launch_bounds__(256)
void k_umfma(const u16* __restrict__ ph, const u16* __restrict__ plo,
             const u16* __restrict__ qth, const u16* __restrict__ qtl,
             const float* __restrict__ ctx, const float* __restrict__ h,
             float* __restrict__ out) {
  const int b = blockIdx.y;
  const int mblk = blockIdx.x >> 1, nb = blockIdx.x & 1;
  const int m0 = mblk * 64;
  const int w = threadIdx.x >> 6, lane = threadIdx.x & 63;
  const int lr = lane & 15, lg = lane >> 4;
  const int n0 = nb * 256 + w * 64;
  const u16* Ahp = ph  + ((size_t)b*T + m0 + lr)*J + lg*8;
  const u16* Alp = plo + ((size_t)b*T + m0 + lr)*J + lg*8;
  const u16* Bhp = qth + ((size_t)b*D + n0 + lr)*J + lg*8;
  const u16* Blp = qtl + ((size_t)b*D + n0 + lr)*J + lg*8;
  f32x4 acc[4][4];
  #pragma unroll
  for (int i = 0; i < 4; ++i)
    #pragma unroll
    for (int j = 0; j < 4; ++j) acc[i][j] = (f32x4){0.f, 0.f, 0.f, 0.f};
  FragSet f0, f1;
  ld_frags(f0, Ahp, Alp, Bhp, Blp, J, 0);
  for (int k0 = 0; k0 < J; k0 += 64) {
    ld_frags(f1, Ahp, Alp, Bhp, Blp, J, k0 + 32);
    mm3(acc, f0);
    int kn = (k0 + 64 < J) ? k0 + 64 : 0;
    ld_frags(f0, Ahp, Alp, Bhp, Blp, J, kn);
    mm3(acc, f1);
  }
  float hv[4];
  #pragma unroll
  for (int nj = 0; nj < 4; ++nj) hv[nj] = h[(size_t)b*D + n0 + nj*16 + lr];
  const float* Cb = ctx + (size_t)b * T * D;
  float* ob = out + (size_t)b * T * (size_t)(4 * D);
  #pragma unroll
  for (int mi = 0; mi < 4; ++mi)
    #pragma unroll
    for (int r = 0; r < 4; ++r) {
      int t = m0 + mi*16 + lg*4 + r;
      const float* crow = Cb + (size_t)t * D;
      float* orow = ob + (size_t)t * 2048;
      #pragma unroll
      for (int nj = 0; nj < 4; ++nj) {
        int d = n0 + nj*16 + lr;
        float u = acc[mi][nj][r];
        float c = crow[d];
        orow[d]          = c;
        orow[512  + d]   = u;
        orow[1024 + d]   = c * u;
        orow[1536 + d]   = c * hv[nj];
      }
    }
}

extern "C" void kernel_launch(void* const* d_in, const int* in_sizes, int n_in,
                              void* d_out, int out_size, void* d_ws, size_t ws_size,
                              hipStream_t stream) {
  const float* context = (const float*)d_in[0];
  const float* query   = (const float*)d_in[1];
  const float* w_alpha = (const float*)d_in[2];
  float* out = (float*)d_out;
  float* ws  = (float*)d_ws;

  float* S    = ws + OFF_S;
  u16*   ch   = (u16*)(ws + OFF_CH);
  u16*   cl   = (u16*)(ws + OFF_CL);
  u16*   qph  = (u16*)(ws + OFF_QPH);
  u16*   qpl  = (u16*)(ws + OFF_QPL);
  u16*   qth  = (u16*)(ws + OFF_QTH);
  u16*   qtl  = (u16*)(ws + OFF_QTL);
  u16*   phb  = (u16*)(ws + OFF_PH);
  u16*   plb  = (u16*)(ws + OFF_PLO);
  float* rt   = ws + OFF_RT;
  float* ct   = ws + OFF_CT;
  float* mcol = ws + OFF_M;
  float* invl = ws + OFF_IL;
  float* rm   = ws + OFF_RM;
  float* bt   = ws + OFF_BT;
  float* h    = ws + OFF_H;
  float* pm   = ws + OFF_PM;
  float* pl2  = ws + OFF_PL2;

  hipMemsetAsync(h, 0, (size_t)B * D * sizeof(float), stream);

  k_prep_c<<<dim3(B * T / 4), 256, 0, stream>>>(context, w_alpha, rt, ch, cl);
  k_prep_q<<<dim3(B * J / 4), 256, 0, stream>>>(query, w_alpha, ct, qph, qpl);
  k_qt    <<<dim3(32, B), 256, 0, stream>>>(query, qth, qtl);
  k_sgemm_mfma<<<dim3(16, B), 256, 0, stream>>>(ch, cl, qph, qpl, rt, ct, S, pm, pl2, rm);
  k_colcombine<<<dim3(B), 256, 0, stream>>>(pm, pl2, mcol, invl);
  k_btsm  <<<dim3(B), 256, 0, stream>>>(rm, bt);
  k_h     <<<dim3(8, B), 256, 0, stream>>>(context, bt, h);
  k_pexp  <<<dim3(B * T / 4), 256, 0, stream>>>(S, mcol, invl, phb, plb);
  k_umfma <<<dim3(32, B), 256, 0, stream>>>(phb, plb, qth, qtl, context, h, out);
}

// Round 2
// 442.270 us; speedup vs baseline: 1.3074x; 1.2065x over previous
//
#include <hip/hip_runtime.h>
#include <cmath>

constexpr int B = 32, T = 1024, J = 256, D = 512;

typedef __attribute__((ext_vector_type(8))) short bf16x8;
typedef __attribute__((ext_vector_type(4))) float f32x4;
typedef __attribute__((ext_vector_type(8))) unsigned short u16x8;
typedef __attribute__((ext_vector_type(4))) unsigned short u16x4;
using u16 = unsigned short;

// ---- workspace layout (float units) ----
constexpr size_t OFF_S   = 0;                                 // S[b,t,j] fp32
constexpr size_t OFF_QPH = OFF_S   + (size_t)B*T*J;           // (q*w3) hi bf16
constexpr size_t OFF_QPL = OFF_QPH + (size_t)B*J*D/2;         // (q*w3) lo
constexpr size_t OFF_QTH = OFF_QPL + (size_t)B*J*D/2;         // q^T hi  [D][J]
constexpr size_t OFF_QTL = OFF_QTH + (size_t)B*J*D/2;         // q^T lo
constexpr size_t OFF_CT  = OFF_QTL + (size_t)B*J*D/2;         // query@w2
constexpr size_t OFF_M   = OFF_CT  + (size_t)B*J;             // col max
constexpr size_t OFF_IL  = OFF_M   + (size_t)B*J;             // 1/col sumexp
constexpr size_t OFF_RM  = OFF_IL  + (size_t)B*J;             // row max
constexpr size_t OFF_BT  = OFF_RM  + (size_t)B*T;             // b_t softmax
constexpr size_t OFF_H   = OFF_BT  + (size_t)B*T;             // h[b,d]
constexpr size_t OFF_PM  = OFF_H   + (size_t)B*D;             // partial col max (8 mblk)
constexpr size_t OFF_PL2 = OFF_PM  + (size_t)B*8*J;           // partial col sumexp

__device__ __forceinline__ u16 f2bf(float x) {
  unsigned u = __float_as_uint(x);
  u += 0x7FFFu + ((u >> 16) & 1u);
  return (u16)(u >> 16);
}
__device__ __forceinline__ float bf2f(u16 h) {
  return __uint_as_float((unsigned)h << 16);
}

// LDS tile addressing: rows of 32 bf16 (64 B), 4 chunks of 8 bf16 (16 B).
// slot = chunk ^ ((row>>1)&3) spreads ds_read_b128/ds_write_b128 across all
// 8 (parity x slot) bank positions -> conflict floor. Returns u16 index.
__device__ __forceinline__ int swz(int row, int c) {
  return row * 32 + ((c ^ ((row >> 1) & 3)) << 3);
}

__device__ __forceinline__ void mm3(f32x4 acc[4][4],
    const bf16x8 ah[4], const bf16x8 al[4],
    const bf16x8 bh[4], const bf16x8 bl[4]) {
  #pragma unroll
  for (int i = 0; i < 4; ++i)
    #pragma unroll
    for (int j = 0; j < 4; ++j) {
      f32x4 a = acc[i][j];
      a = __builtin_amdgcn_mfma_f32_16x16x32_bf16(ah[i], bh[j], a, 0, 0, 0);
      a = __builtin_amdgcn_mfma_f32_16x16x32_bf16(ah[i], bl[j], a, 0, 0, 0);
      a = __builtin_amdgcn_mfma_f32_16x16x32_bf16(al[i], bh[j], a, 0, 0, 0);
      acc[i][j] = a;
    }
}

// ---------- query prep: ct = q.w2 ; q*w3 -> hi/lo bf16 ----------
__global__ void k_prep_q(const float* __restrict__ q, const float* __restrict__ w_alpha,
                         float* __restrict__ ct, u16* __restrict__ qph, u16* __restrict__ qpl) {
  int wid = threadIdx.x >> 6, lane = threadIdx.x & 63;
  size_t row = (size_t)blockIdx.x * 4 + wid;
  const float4* q4 = (const float4*)(q + row * D);
  const float4* w2 = (const float4*)(w_alpha + D);
  const float4* w3 = (const float4*)(w_alpha + 2 * D);
  float4 a0 = q4[lane*2], a1 = q4[lane*2+1];
  float4 b0 = w2[lane*2], b1 = w2[lane*2+1];
  float4 c0 = w3[lane*2], c1 = w3[lane*2+1];
  float acc = a0.x*b0.x + a0.y*b0.y + a0.z*b0.z + a0.w*b0.w
            + a1.x*b1.x + a1.y*b1.y + a1.z*b1.z + a1.w*b1.w;
  float v[8] = {a0.x*c0.x, a0.y*c0.y, a0.z*c0.z, a0.w*c0.w,
                a1.x*c1.x, a1.y*c1.y, a1.z*c1.z, a1.w*c1.w};
  u16x8 hv, lv;
  #pragma unroll
  for (int i = 0; i < 8; ++i) {
    u16 hb = f2bf(v[i]);
    hv[i] = hb;
    lv[i] = f2bf(v[i] - bf2f(hb));
  }
  *(u16x8*)(qph + row*D + lane*8) = hv;
  *(u16x8*)(qpl + row*D + lane*8) = lv;
  #pragma unroll
  for (int off = 32; off; off >>= 1) acc += __shfl_down(acc, off);
  if (lane == 0) ct[row] = acc;
}

// ---------- query transpose: q[J][D] -> qt hi/lo [D][J] ----------
__global__ void k_qt(const float* __restrict__ q, u16* __restrict__ qth, u16* __restrict__ qtl) {
  __shared__ float tl[64][65];
  int b = blockIdx.y;
  int j0 = (blockIdx.x & 3) * 64;
  int d0 = (blockIdx.x >> 2) * 64;
  int r = threadIdx.x >> 4, c = threadIdx.x & 15;
  #pragma unroll
  for (int rr = 0; rr < 4; ++rr) {
    int jl = r + rr*16;
    float4 v = *(const float4*)(q + ((size_t)b*J + j0 + jl)*D + d0 + c*4);
    tl[jl][c*4+0] = v.x; tl[jl][c*4+1] = v.y; tl[jl][c*4+2] = v.z; tl[jl][c*4+3] = v.w;
  }
  __syncthreads();
  #pragma unroll
  for (int rr = 0; rr < 4; ++rr) {
    int dl = r + rr*16;
    u16x4 hv, lv;
    #pragma unroll
    for (int k = 0; k < 4; ++k) {
      float v = tl[c*4+k][dl];
      u16 hb = f2bf(v);
      hv[k] = hb;
      lv[k] = f2bf(v - bf2f(hb));
    }
    size_t o = ((size_t)b*D + d0 + dl)*J + j0 + c*4;
    *(u16x4*)(qth + o) = hv;
    *(u16x4*)(qtl + o) = lv;
  }
}

// ---------- S = c @ qp^T + rt + ct ; fused rt, col-partials, rowmax ----------
// BM=128, BN=256(full J), BK=32. 8 waves (2x4), wave-tile 64x64. LDS ~56.5 KB.
__global__ __launch_bounds__(512, 2)
void k_sgemm2(const float* __restrict__ ctx, const u16* __restrict__ qph,
              const u16* __restrict__ qpl, const float* __restrict__ w_alpha,
              const float* __restrict__ ct, float* __restrict__ S,
              float* __restrict__ pm, float* __restrict__ pl, float* __restrict__ rm) {
  __shared__ __align__(16) u16 Ah[128*32], Al[128*32], Bh[256*32], Bl[256*32];
  __shared__ float w1s[512];
  __shared__ float rts[128];
  __shared__ float pcm[2][256], pcl[2][256];
  __shared__ float rmx[4][128];
  const int bid = blockIdx.x;
  const int wg = (bid & 7) * 32 + (bid >> 3);      // XCD-contiguous: 4 batches/XCD
  const int b = wg >> 3, mblk = wg & 7;
  const int m0 = mblk * 128;
  const int tid = threadIdx.x;
  const int lane = tid & 63, w = tid >> 6;
  const int lr = lane & 15, lg = lane >> 4;
  const int wr = w >> 2, wc = w & 3;
  const int arow = tid >> 2, ac = tid & 3;         // staging roles
  w1s[tid & 511] = w_alpha[tid & 511];
  const float* Cb = ctx + ((size_t)b*T + m0) * D;
  const u16* Bhg = qph + (size_t)b*J*D;
  const u16* Blg = qpl + (size_t)b*J*D;
  f32x4 acc[4][4];
  #pragma unroll
  for (int i = 0; i < 4; ++i)
    #pragma unroll
    for (int j = 0; j < 4; ++j) acc[i][j] = (f32x4){0.f, 0.f, 0.f, 0.f};
  float rtacc = 0.f;
  float4 a0, a1;
  bf16x8 qh0, qh1, ql0, ql1;
  // prologue loads (k0 = 0)
  a0 = *(const float4*)(Cb + (size_t)arow*D + ac*8);
  a1 = *(const float4*)(Cb + (size_t)arow*D + ac*8 + 4);
  qh0 = *(const bf16x8*)(Bhg + (size_t)arow*D + ac*8);
  ql0 = *(const bf16x8*)(Blg + (size_t)arow*D + ac*8);
  qh1 = *(const bf16x8*)(Bhg + (size_t)(arow+128)*D + ac*8);
  ql1 = *(const bf16x8*)(Blg + (size_t)(arow+128)*D + ac*8);
  __syncthreads();                                 // w1s visible
  for (int ks = 0; ks < 16; ++ks) {
    __syncthreads();                               // prev frag reads done
    float av[8] = {a0.x,a0.y,a0.z,a0.w,a1.x,a1.y,a1.z,a1.w};
    u16x8 hh, ll;
    #pragma unroll
    for (int i = 0; i < 8; ++i) {
      u16 hb = f2bf(av[i]);
      hh[i] = hb;
      ll[i] = f2bf(av[i] - bf2f(hb));
    }
    *(u16x8*)&Ah[swz(arow, ac)] = hh;
    *(u16x8*)&Al[swz(arow, ac)] = ll;
    *(bf16x8*)&Bh[swz(arow, ac)]     = qh0;
    *(bf16x8*)&Bl[swz(arow, ac)]     = ql0;
    *(bf16x8*)&Bh[swz(arow+128, ac)] = qh1;
    *(bf16x8*)&Bl[swz(arow+128, ac)] = ql1;
    // rt partial dot (uses staged regs + static w1s)
    const int kb = ks*32 + ac*8;
    rtacc += av[0]*w1s[kb+0] + av[1]*w1s[kb+1] + av[2]*w1s[kb+2] + av[3]*w1s[kb+3]
           + av[4]*w1s[kb+4] + av[5]*w1s[kb+5] + av[6]*w1s[kb+6] + av[7]*w1s[kb+7];
    __syncthreads();                               // staging visible
    if (ks < 15) {                                 // early-issue next loads
      const int k0 = (ks + 1) * 32;
      a0 = *(const float4*)(Cb + (size_t)arow*D + k0 + ac*8);
      a1 = *(const float4*)(Cb + (size_t)arow*D + k0 + ac*8 + 4);
      qh0 = *(const bf16x8*)(Bhg + (size_t)arow*D + k0 + ac*8);
      ql0 = *(const bf16x8*)(Blg + (size_t)arow*D + k0 + ac*8);
      qh1 = *(const bf16x8*)(Bhg + (size_t)(arow+128)*D + k0 + ac*8);
      ql1 = *(const bf16x8*)(Blg + (size_t)(arow+128)*D + k0 + ac*8);
    }
    bf16x8 fah[4], fal[4], fbh[4], fbl[4];
    #pragma unroll
    for (int i = 0; i < 4; ++i) {
      int ar = wr*64 + i*16 + lr;
      int br = wc*64 + i*16 + lr;
      fah[i] = *(const bf16x8*)&Ah[swz(ar, lg)];
      fal[i] = *(const bf16x8*)&Al[swz(ar, lg)];
      fbh[i] = *(const bf16x8*)&Bh[swz(br, lg)];
      fbl[i] = *(const bf16x8*)&Bl[swz(br, lg)];
    }
    mm3(acc, fah, fal, fbh, fbl);
  }
  // rt reduce over the 4 chunk-lanes
  rtacc += __shfl_xor(rtacc, 1);
  rtacc += __shfl_xor(rtacc, 2);
  if ((lane & 3) == 0) rts[arow] = rtacc;
  __syncthreads();
  // add rt + ct
  float cv[4];
  #pragma unroll
  for (int nj = 0; nj < 4; ++nj) cv[nj] = ct[(size_t)b*J + wc*64 + nj*16 + lr];
  #pragma unroll
  for (int mi = 0; mi < 4; ++mi)
    #pragma unroll
    for (int r = 0; r < 4; ++r) {
      float rv = rts[wr*64 + mi*16 + lg*4 + r];
      #pragma unroll
      for (int nj = 0; nj < 4; ++nj) acc[mi][nj][r] += rv + cv[nj];
    }
  // store S
  float* Sb = S + ((size_t)b*T + m0)*J;
  #pragma unroll
  for (int mi = 0; mi < 4; ++mi)
    #pragma unroll
    for (int r = 0; r < 4; ++r) {
      size_t ro = (size_t)(wr*64 + mi*16 + lg*4 + r) * J;
      #pragma unroll
      for (int nj = 0; nj < 4; ++nj)
        Sb[ro + wc*64 + nj*16 + lr] = acc[mi][nj][r];
    }
  // column partial stats over this wave's 64 rows
  #pragma unroll
  for (int nj = 0; nj < 4; ++nj) {
    float m = -INFINITY;
    #pragma unroll
    for (int mi = 0; mi < 4; ++mi)
      #pragma unroll
      for (int r = 0; r < 4; ++r) m = fmaxf(m, acc[mi][nj][r]);
    m = fmaxf(m, __shfl_xor(m, 16));
    m = fmaxf(m, __shfl_xor(m, 32));
    float s = 0.f;
    #pragma unroll
    for (int mi = 0; mi < 4; ++mi)
      #pragma unroll
      for (int r = 0; r < 4; ++r) s += __expf(acc[mi][nj][r] - m);
    s += __shfl_xor(s, 16);
    s += __shfl_xor(s, 32);
    if (lg == 0) {
      pcm[wr][wc*64 + nj*16 + lr] = m;
      pcl[wr][wc*64 + nj*16 + lr] = s;
    }
  }
  // row max over this wave's 64 cols
  #pragma unroll
  for (int mi = 0; mi < 4; ++mi)
    #pragma unroll
    for (int r = 0; r < 4; ++r) {
      float m = -INFINITY;
      #pragma unroll
      for (int nj = 0; nj < 4; ++nj) m = fmaxf(m, acc[mi][nj][r]);
      m = fmaxf(m, __shfl_xor(m, 1));
      m = fmaxf(m, __shfl_xor(m, 2));
      m = fmaxf(m, __shfl_xor(m, 4));
      m = fmaxf(m, __shfl_xor(m, 8));
      if (lr == 0) rmx[wc][wr*64 + mi*16 + lg*4 + r] = m;
    }
  __syncthreads();
  if (tid < 256) {
    float m0v = pcm[0][tid], m1v = pcm[1][tid];
    float mm = fmaxf(m0v, m1v);
    float lsum = pcl[0][tid]*__expf(m0v - mm) + pcl[1][tid]*__expf(m1v - mm);
    pm[((size_t)b*8 + mblk)*J + tid] = mm;
    pl[((size_t)b*8 + mblk)*J + tid] = lsum;
  } else if (tid < 384) {
    int t = tid - 256;
    float m = fmaxf(fmaxf(rmx[0][t], rmx[1][t]), fmaxf(rmx[2][t], rmx[3][t]));
    rm[(size_t)b*T + m0 + t] = m;
  }
}

// ---------- combine 8 column partials ----------
__global__ void k_colcombine(const float* __restrict__ pm, const float* __restrict__ pl,
                             float* __restrict__ mcol, float* __restrict__ invl) {
  int b = blockIdx.x, j = threadIdx.x;
  float m = -INFINITY, l = 0.f;
  for (int c = 0; c < 8; ++c) {
    float pmv = pm[((size_t)b * 8 + c) * J + j];
    float plv = pl[((size_t)b * 8 + c) * J + j];
    float mn = fmaxf(m, pmv);
    l = l * __expf(m - mn) + plv * __expf(pmv - mn);
    m = mn;
  }
  mcol[b * J + j] = m;
  invl[b * J + j] = 1.f / l;
}

// ---------- b_t = softmax over t of rowmax ----------
__global__ void k_btsm(const float* __restrict__ rm, float* __restrict__ bt) {
  __shared__ float red[4];
  int b = blockIdx.x, tid = threadIdx.x;
  int wid = tid >> 6, lane = tid & 63;
  float4 x = ((const float4*)(rm + (size_t)b * T))[tid];
  float m = fmaxf(fmaxf(x.x, x.y), fmaxf(x.z, x.w));
  #pragma unroll
  for (int off = 32; off; off >>= 1) m = fmaxf(m, __shfl_down(m, off));
  if (lane == 0) red[wid] = m;
  __syncthreads();
  float M = fmaxf(fmaxf(red[0], red[1]), fmaxf(red[2], red[3]));
  float e0 = __expf(x.x - M), e1 = __expf(x.y - M), e2 = __expf(x.z - M), e3 = __expf(x.w - M);
  float s = e0 + e1 + e2 + e3;
  #pragma unroll
  for (int off = 32; off; off >>= 1) s += __shfl_down(s, off);
  __syncthreads();
  if (lane == 0) red[wid] = s;
  __syncthreads();
  float inv = 1.f / (red[0] + red[1] + red[2] + red[3]);
  ((float4*)(bt + (size_t)b * T))[tid] = make_float4(e0 * inv, e1 * inv, e2 * inv, e3 * inv);
}

// ---------- h[b,d] = sum_t bt * context ----------
__global__ void k_h(const float* __restrict__ C, const float* __restrict__ bt,
                    float* __restrict__ h) {
  int b = blockIdx.y, chunk = blockIdx.x, tid = threadIdx.x;
  const float* Cb = C + (size_t)b * T * D + (size_t)chunk * 64 * D;
  const float* wb = bt + b * T + chunk * 64;
  float2 acc = make_float2(0.f, 0.f);
  for (int t = 0; t < 64; ++t) {
    float w = wb[t];
    float2 v = ((const float2*)(Cb + (size_t)t * D))[tid];
    acc.x = fmaf(w, v.x, acc.x);
    acc.y = fmaf(w, v.y, acc.y);
  }
  atomicAdd(&h[b * D + tid * 2],     acc.x);
  atomicAdd(&h[b * D + tid * 2 + 1], acc.y);
}

// ---------- U = P @ q with in-staging exp/split, fused G assembly ----------
// BM=128, BN=256 (N=512 split in nb), BK=32, 8 waves. LDS ~50 KB.
__global__ __launch_bounds__(512, 2)
void k_umfma2(const float* __restrict__ S, const u16* __restrict__ qth,
              const u16* __restrict__ qtl, const float* __restrict__ mcol,
              const float* __restrict__ invl, const float* __restrict__ ctx,
              const float* __restrict__ h, float* __restrict__ out) {
  __shared__ __align__(16) u16 Ah[128*32], Al[128*32], Bh[256*32], Bl[256*32];
  __shared__ float msl[256], isl[256];
  const int bid = blockIdx.x;
  const int wg = (bid & 7) * 64 + (bid >> 3);      // XCD-contiguous: 4 batches/XCD
  const int b = wg >> 4, rest = wg & 15;
  const int mblk = rest >> 1, nb = rest & 1;
  const int m0 = mblk * 128, n0 = nb * 256;
  const int tid = threadIdx.x;
  const int lane = tid & 63, w = tid >> 6;
  const int lr = lane & 15, lg = lane >> 4;
  const int wr = w >> 2, wc = w & 3;
  const int arow = tid >> 2, ac = tid & 3;
  if (tid < 256) {
    msl[tid] = mcol[(size_t)b*J + tid];
    isl[tid] = invl[(size_t)b*J + tid];
  }
  const float* Sb = S + ((size_t)b*T + m0)*J;
  const u16* Bhg = qth + ((size_t)b*D + n0)*J;
  const u16* Blg = qtl + ((size_t)b*D + n0)*J;
  f32x4 acc[4][4];
  #pragma unroll
  for (int i = 0; i < 4; ++i)
    #pragma unroll
    for (int j = 0; j < 4; ++j) acc[i][j] = (f32x4){0.f, 0.f, 0.f, 0.f};
  float4 a0, a1;
  bf16x8 qh0, qh1, ql0, ql1;
  a0 = *(const float4*)(Sb + (size_t)arow*J + ac*8);
  a1 = *(const float4*)(Sb + (size_t)arow*J + ac*8 + 4);
  qh0 = *(const bf16x8*)(Bhg + (size_t)arow*J + ac*8);
  ql0 = *(const bf16x8*)(Blg + (size_t)arow*J + ac*8);
  qh1 = *(const bf16x8*)(Bhg + (size_t)(arow+128)*J + ac*8);
  ql1 = *(const bf16x8*)(Blg + (size_t)(arow+128)*J + ac*8);
  __syncthreads();                                 // msl/isl visible
  for (int ks = 0; ks < 8; ++ks) {
    __syncthreads();
    float av[8] = {a0.x,a0.y,a0.z,a0.w,a1.x,a1.y,a1.z,a1.w};
    const int jb = ks*32 + ac*8;
    u16x8 hh, ll;
    #pragma unroll
    for (int i = 0; i < 8; ++i) {
      float p = __expf(av[i] - msl[jb+i]) * isl[jb+i];
      u16 hb = f2bf(p);
      hh[i] = hb;
      ll[i] = f2bf(p - bf2f(hb));
    }
    *(u16x8*)&Ah[swz(arow, ac)] = hh;
    *(u16x8*)&Al[swz(arow, ac)] = ll;
    *(bf16x8*)&Bh[swz(arow, ac)]     = qh0;
    *(bf16x8*)&Bl[swz(arow, ac)]     = ql0;
    *(bf16x8*)&Bh[swz(arow+128, ac)] = qh1;
    *(bf16x8*)&Bl[swz(arow+128, ac)] = ql1;
    __syncthreads();
    if (ks < 7) {
      const int k0 = (ks + 1) * 32;
      a0 = *(const float4*)(Sb + (size_t)arow*J + k0 + ac*8);
      a1 = *(const float4*)(Sb + (size_t)arow*J + k0 + ac*8 + 4);
      qh0 = *(const bf16x8*)(Bhg + (size_t)arow*J + k0 + ac*8);
      ql0 = *(const bf16x8*)(Blg + (size_t)arow*J + k0 + ac*8);
      qh1 = *(const bf16x8*)(Bhg + (size_t)(arow+128)*J + k0 + ac*8);
      ql1 = *(const bf16x8*)(Blg + (size_t)(arow+128)*J + k0 + ac*8);
    }
    bf16x8 fah[4], fal[4], fbh[4], fbl[4];
    #pragma unroll
    for (int i = 0; i < 4; ++i) {
      int ar = wr*64 + i*16 + lr;
      int br = wc*64 + i*16 + lr;
      fah[i] = *(const bf16x8*)&Ah[swz(ar, lg)];
      fal[i] = *(const bf16x8*)&Al[swz(ar, lg)];
      fbh[i] = *(const bf16x8*)&Bh[swz(br, lg)];
      fbl[i] = *(const bf16x8*)&Bl[swz(br, lg)];
    }
    mm3(acc, fah, fal, fbh, fbl);
  }
  // epilogue: G = [c, U, c*U, c*h]
  float hv[4];
  #pragma unroll
  for (int nj = 0; nj < 4; ++nj) hv[nj] = h[(size_t)b*D + n0 + wc*64 + nj*16 + lr];
  const float* Cb = ctx + ((size_t)b*T + m0) * D;
  float* ob = out + ((size_t)b*T + m0) * 2048;
  #pragma unroll
  for (int mi = 0; mi < 4; ++mi)
    #pragma unroll
    for (int r = 0; r < 4; ++r) {
      int trow = wr*64 + mi*16 + lg*4 + r;
      const float* crow = Cb + (size_t)trow * D;
      float* orow = ob + (size_t)trow * 2048;
      #pragma unroll
      for (int nj = 0; nj < 4; ++nj) {
        int d = n0 + wc*64 + nj*16 + lr;
        float u = acc[mi][nj][r];
        float c = crow[d];
        orow[d]        = c;
        orow[512 + d]  = u;
        orow[1024 + d] = c * u;
        orow[1536 + d] = c * hv[nj];
      }
    }
}

extern "C" void kernel_launch(void* const* d_in, const int* in_sizes, int n_in,
                              void* d_out, int out_size, void* d_ws, size_t ws_size,
                              hipStream_t stream) {
  const float* context = (const float*)d_in[0];
  const float* query   = (const float*)d_in[1];
  const float* w_alpha = (const float*)d_in[2];
  float* out = (float*)d_out;
  float* ws  = (float*)d_ws;

  float* S    = ws + OFF_S;
  u16*   qph  = (u16*)(ws + OFF_QPH);
  u16*   qpl  = (u16*)(ws + OFF_QPL);
  u16*   qth  = (u16*)(ws + OFF_QTH);
  u16*   qtl  = (u16*)(ws + OFF_QTL);
  float* ct   = ws + OFF_CT;
  float* mcol = ws + OFF_M;
  float* invl = ws + OFF_IL;
  float* rm   = ws + OFF_RM;
  float* bt   = ws + OFF_BT;
  float* h    = ws + OFF_H;
  float* pm   = ws + OFF_PM;
  float* pl2  = ws + OFF_PL2;

  hipMemsetAsync(h, 0, (size_t)B * D * sizeof(float), stream);

  k_prep_q<<<dim3(B * J / 4), 256, 0, stream>>>(query, w_alpha, ct, qph, qpl);
  k_qt    <<<dim3(32, B), 256, 0, stream>>>(query, qth, qtl);
  k_sgemm2<<<dim3(256), 512, 0, stream>>>(context, qph, qpl, w_alpha, ct, S, pm, pl2, rm);
  k_colcombine<<<dim3(B), 256, 0, stream>>>(pm, pl2, mcol, invl);
  k_btsm  <<<dim3(B), 256, 0, stream>>>(rm, bt);
  k_h     <<<dim3(16, B), 256, 0, stream>>>(context, bt, h);
  k_umfma2<<<dim3(512), 512, 0, stream>>>(S, qth, qtl, mcol, invl, context, h, out);
}